// Round 4
// baseline (233.140 us; speedup 1.0000x reference)
//
#include <hip/hip_runtime.h>
#include <cmath>

#define TPB 256
typedef float floatx4 __attribute__((ext_vector_type(4)));
typedef __bf16 bf16x8 __attribute__((ext_vector_type(8)));
typedef unsigned short ushort8 __attribute__((ext_vector_type(8)));
typedef unsigned int uint2v __attribute__((ext_vector_type(2)));
typedef unsigned short ushort_t;

// ---------- workspace layout (float units) ----------
// [0]=sc2d ((S_N1*s_w2)/S_N2), [1]=sc3d ((S_N2*s_w3)/S_N3), [2]=K1 ((S_X1*s_w1)/S_N1)
// [16..88) = pmn[72] partial mins, [96..168) = pmx[72] partial maxes
// [256..512) = fc12 per-group tickets (int), zeroed by k_conv12 blocks 0..255
#define OFF_PMN 16
#define OFF_PMX 96
#define OFF_TICK 256
#define OFF_B1 520       // 20  f32  (pre-divided by S_N1)
#define OFF_B2 544       // 50  f32  (pre-divided by S_N2)
#define OFF_B3 600       // 500 f32  (pre-divided by S_N3)
#define W1BF_BYTE 6144       // [32][32] u16 int weights (conv1)
#define W2BF_BYTE 8192       // [20 chunks][64 co][32 k] u16 int weights (conv2), 81920 B
#define W3BF_BYTE 131072     // [512][800]  u16 int weights (fc1)
#define PART_BYTE 1048576    // [4][B][10] f32 fc2 partial logits — in gap before q2
#define Q2_BYTE  29360128ULL // [B][800] bf16 (6.6 MB)

#define S_X1 (3.5f/255.0f)
#define ZP_X1 36.0f
#define S_N1 (6.0f/255.0f)
#define S_N2 (8.0f/255.0f)
#define S_N3 (10.0f/255.0f)

// LDS pixel stride for conv2 A-reads: 40 u16 = 80 B = 20 banks (period-32 -> conflict-free)
#define XSTR 40
#define NCG 4   // fc1/fc2 column groups (each block covers 128 of 512 cols)

__device__ inline float qclip(float x, float s, float zp){
    return rintf(fminf(fmaxf(zp + x / s, 0.0f), 255.0f));
}
// exact bf16 bits for integer-valued floats |v| < 256
__device__ inline ushort_t bfbits(float v){
    return (ushort_t)(__float_as_uint(v) >> 16);
}

// per-block min/max partials; block->tensor map: 0:c1w 1:c1b 2-5:c2w 6:c2b 7-70:f1w 71:f1b
__global__ __launch_bounds__(TPB) void k_minmax(
        const float* c1w, const float* c1b, const float* c2w, const float* c2b,
        const float* f1w, const float* f1b, float* pmn, float* pmx){
    __shared__ float smn[TPB], smx[TPB];
    int bb = blockIdx.x, tid = threadIdx.x;
    const float* src; int n, sub, nsub;
    if      (bb == 0){ src=c1w; n=500;    sub=0;     nsub=1;  }
    else if (bb == 1){ src=c1b; n=20;     sub=0;     nsub=1;  }
    else if (bb <  6){ src=c2w; n=25000;  sub=bb-2;  nsub=4;  }
    else if (bb == 6){ src=c2b; n=50;     sub=0;     nsub=1;  }
    else if (bb < 71){ src=f1w; n=400000; sub=bb-7;  nsub=64; }
    else             { src=f1b; n=500;    sub=0;     nsub=1;  }
    float mn = INFINITY, mx = -INFINITY;
    for (int i = sub*TPB + tid; i < n; i += nsub*TPB){
        float v = src[i]; mn = fminf(mn, v); mx = fmaxf(mx, v);
    }
    smn[tid] = mn; smx[tid] = mx; __syncthreads();
    for (int s = TPB/2; s > 0; s >>= 1){
        if (tid < s){
            smn[tid] = fminf(smn[tid], smn[tid+s]);
            smx[tid] = fmaxf(smx[tid], smx[tid+s]);
        }
        __syncthreads();
    }
    if (tid == 0){ pmn[bb] = smn[0]; pmx[bb] = smx[0]; }
}

// w2bt chunk packing (20 chunks of K=32):
//   main c in 0..12:   oct q -> tap = 2c + (q>>1), ci = (q&1)*8 + jj   (tap 25 -> zero)
//   residue c in 13..19: oct q -> tap = 4(c-13) + q, ci = 16 + jj (jj<4; jj>=4 -> zero)
#define N_EFF 452157
__global__ __launch_bounds__(TPB) void k_make_eff(
        const float* c1w, const float* c1b, const float* c2w, const float* c2b,
        const float* f1w, const float* f1b, const float* pmn, const float* pmx,
        float* ws, ushort_t* w1bf, ushort_t* w2bf, ushort_t* w3bf){
    __shared__ float sS[6], sZ[6];
    int tid = threadIdx.x;
    int wv = tid >> 6, lane = tid & 63;
    const int starts[6] = {0,1,2,6,7,71};
    const int counts[6] = {1,1,4,1,64,1};
    #pragma unroll
    for (int rep = 0; rep < 2; ++rep){
        int t = wv + rep*4;
        if (t < 6){
            float mn = INFINITY, mx = -INFINITY;
            if (lane < counts[t]){ mn = pmn[starts[t]+lane]; mx = pmx[starts[t]+lane]; }
            #pragma unroll
            for (int off = 32; off > 0; off >>= 1){
                mn = fminf(mn, __shfl_xor(mn, off));
                mx = fmaxf(mx, __shfl_xor(mx, off));
            }
            if (lane == 0){
                float s = (mx - mn) / 255.0f;
                sS[t] = s;
                sZ[t] = truncf(fminf(fmaxf(0.0f - mn / s, 0.0f), 255.0f));
            }
        }
    }
    __syncthreads();

    int i = blockIdx.x * TPB + tid;
    if (i >= N_EFF) return;
    if (i < 1024){                   // w1bf: [n(32)][k(32)] integer weights
        int n = i >> 5, k = i & 31;
        float v = 0.0f;
        if (n < 20 && k < 25) v = qclip(c1w[n*25 + k], sS[0], sZ[0]) - sZ[0];
        w1bf[i] = bfbits(v);
    } else if (i < 1044){            // b1 pre-divided by S_N1
        int j = i - 1024;
        ws[OFF_B1 + j] = (sS[1] * (qclip(c1b[j], sS[1], sZ[1]) + sZ[1])) / S_N1;
    } else if (i < 42004){           // w2bt chunk-packed
        int j = i - 1044;
        int c = j >> 11, r = j & 2047, co = r >> 5, k = r & 31;
        int q = k >> 3, jj = k & 7;
        int tap, ci; bool valid;
        if (c < 13){ tap = 2*c + (q>>1); ci = (q&1)*8 + jj; valid = (tap < 25); }
        else       { tap = 4*(c-13) + q; ci = 16 + jj;      valid = (tap < 25) && (jj < 4); }
        valid = valid && (co < 50);
        float v = 0.0f;
        if (valid) v = qclip(c2w[(co*20 + ci)*25 + tap], sS[2], sZ[2]) - sZ[2];
        w2bf[j] = bfbits(v);
    } else if (i < 42054){           // b2 pre-divided by S_N2
        int j = i - 42004;
        ws[OFF_B2 + j] = (sS[3] * (qclip(c2b[j], sS[3], sZ[3]) + sZ[3])) / S_N2;
    } else if (i < 451654){          // w3bf: [n(512)][k(800)]
        int j = i - 42054;
        int n = j / 800, k = j - 800*n;
        float v = 0.0f;
        if (n < 500) v = qclip(f1w[n*800 + k], sS[4], sZ[4]) - sZ[4];
        w3bf[j] = bfbits(v);
    } else if (i < 452154){          // b3 pre-divided by S_N3
        int j = i - 451654;
        ws[OFF_B3 + j] = (sS[5] * (qclip(f1b[j], sS[5], sZ[5]) + sZ[5])) / S_N3;
    } else if (i == 452154){
        ws[0] = (S_N1 * sS[2]) / S_N2;   // conv2 combined scale, pre-divided
    } else if (i == 452155){
        ws[1] = (S_N2 * sS[4]) / S_N3;   // fc1 combined scale, pre-divided
    } else {
        ws[2] = (S_X1 * sS[0]) / S_N1;   // conv1 combined scale, pre-divided
    }
}

// Fused conv1+conv2, one image per block. (R2-measured 52 µs version, reverted from
// the R3 pair-pack regression.) Also zeroes the fc12 tickets (blocks 0..255) so the
// fused-softmax fc12 needs no workspace zero-init assumption.
__global__ __launch_bounds__(TPB, 4) void k_conv12(const float* x, const ushort_t* w1bf,
                                                   const ushort_t* w2bt, const float* ws,
                                                   ushort_t* q2bf, int* tick, int B){
    __shared__ __align__(16) ushort_t xs[144*XSTR];   // conv2 input, [pool pixel][ci(XSTR)]
    __shared__ __align__(16) ushort_t xim[3136];      // 4 per-quad copies of quantized image
    int b = blockIdx.x, tid = threadIdx.x;
    int lane = tid & 63, wv = tid >> 6;
    int ln = lane & 15, quad = lane >> 4;

    if (tid == 0 && b < 256) tick[b] = 0;   // reset fc12 tickets (fc12 runs after us)

    // zero xs pad columns 20-23 once (ci 24-39 are never read)
    for (int i = tid; i < 144; i += TPB){
        *(unsigned int*)(xs + i*XSTR + 20) = 0u;
        *(unsigned int*)(xs + i*XSTR + 22) = 0u;
    }

    // ---------------- conv1 phase ----------------
    // 784 px = 196 float4 loads; each thread quantizes 4 px, packs 2x u32, writes one
    // b64 per xim copy (byte offsets: copies at 1568*c, 1568%8==0; tid*8 aligned).
    const float* xb = x + (size_t)b * 784;
    if (tid < 196){
        floatx4 v = *(const floatx4*)(xb + tid*4);
        unsigned int qp[2];
        #pragma unroll
        for (int h = 0; h < 2; ++h){
            float q0 = rintf(fminf(fmaxf(ZP_X1 + v[2*h]   / S_X1, 0.0f), 255.0f)) - ZP_X1;
            float q1 = rintf(fminf(fmaxf(ZP_X1 + v[2*h+1] / S_X1, 0.0f), 255.0f)) - ZP_X1;
            qp[h] = (unsigned int)bfbits(q0) | ((unsigned int)bfbits(q1) << 16);
        }
        uint2v qq; qq.x = qp[0]; qq.y = qp[1];
        uint2v* dst = (uint2v*)xim;
        dst[tid]       = qq;
        dst[196 + tid] = qq;
        dst[392 + tid] = qq;
        dst[588 + tid] = qq;
    }

    int offj[8];
    #pragma unroll
    for (int j = 0; j < 8; ++j){
        int k = quad*8 + j;
        int kh = k / 5, kw = k - 5*kh;
        offj[j] = (k < 25) ? (kh*28 + kw) : 0;   // invalid taps read pixel 'base' (wt=0)
    }
    const ushort_t* xq = xim + quad*784;   // this quad's private copy

    ushort8 bw0 = *(const ushort8*)(w1bf + ln*32 + quad*8);
    ushort8 bw1 = *(const ushort8*)(w1bf + (16 + ln)*32 + quad*8);
    bf16x8 bf0 = __builtin_bit_cast(bf16x8, bw0);
    bf16x8 bf1 = __builtin_bit_cast(bf16x8, bw1);

    float K1 = ws[2];
    float B1_0 = ws[OFF_B1 + ln];
    float B1_1 = (ln < 4) ? ws[OFF_B1 + 16 + ln] : 0.0f;
    __syncthreads();

    #pragma unroll 3
    for (int i = 0; i < 9; ++i){
        int mt = 9*wv + i;
        int m = mt*16 + ln;
        int p = m >> 2, crn = m & 3;
        int ph_ = p / 12, pw_ = p - 12*ph_;
        int oh = 2*ph_ + (crn >> 1), ow = 2*pw_ + (crn & 1);
        int base = oh*28 + ow;
        ushort8 aw;
        #pragma unroll
        for (int j = 0; j < 8; ++j)
            aw[j] = xq[base + offj[j]];
        bf16x8 af = __builtin_bit_cast(bf16x8, aw);
        floatx4 z = (floatx4){0.f,0.f,0.f,0.f};
        floatx4 a0 = __builtin_amdgcn_mfma_f32_16x16x32_bf16(af, bf0, z, 0, 0, 0);
        floatx4 a1 = __builtin_amdgcn_mfma_f32_16x16x32_bf16(af, bf1, z, 0, 0, 0);

        int pp = mt*4 + quad;
        {
            float y0 = fmaf(a0[0], K1, B1_0), y1 = fmaf(a0[1], K1, B1_0);
            float y2 = fmaf(a0[2], K1, B1_0), y3 = fmaf(a0[3], K1, B1_0);
            float mA = fmaxf(fmaxf(y0, y1), y2);
            float mf = fmaxf(fmaxf(mA, y3), 0.0f);
            if (__ballot(mf >= 255.5f)){
                // exact mod-256 wrap path (rare)
                unsigned int q0 = ((unsigned int)rintf(fmaxf(y0,0.f))) & 255u;
                unsigned int q1 = ((unsigned int)rintf(fmaxf(y1,0.f))) & 255u;
                unsigned int qq2 = ((unsigned int)rintf(fmaxf(y2,0.f))) & 255u;
                unsigned int q3 = ((unsigned int)rintf(fmaxf(y3,0.f))) & 255u;
                unsigned int h0 = q0 > q1 ? q0 : q1;
                unsigned int h1 = qq2 > q3 ? qq2 : q3;
                mf = (float)(h0 > h1 ? h0 : h1);
            } else {
                mf = rintf(mf);
            }
            xs[pp*XSTR + ln] = bfbits(mf);
        }
        if (ln < 4){
            float y0 = fmaf(a1[0], K1, B1_1), y1 = fmaf(a1[1], K1, B1_1);
            float y2 = fmaf(a1[2], K1, B1_1), y3 = fmaf(a1[3], K1, B1_1);
            float mA = fmaxf(fmaxf(y0, y1), y2);
            float mf = fmaxf(fmaxf(mA, y3), 0.0f);
            if (__ballot(mf >= 255.5f)){
                unsigned int q0 = ((unsigned int)rintf(fmaxf(y0,0.f))) & 255u;
                unsigned int q1 = ((unsigned int)rintf(fmaxf(y1,0.f))) & 255u;
                unsigned int qq2 = ((unsigned int)rintf(fmaxf(y2,0.f))) & 255u;
                unsigned int q3 = ((unsigned int)rintf(fmaxf(y3,0.f))) & 255u;
                unsigned int h0 = q0 > q1 ? q0 : q1;
                unsigned int h1 = qq2 > q3 ? qq2 : q3;
                mf = (float)(h0 > h1 ? h0 : h1);
            } else {
                mf = rintf(mf);
            }
            xs[pp*XSTR + 16 + ln] = bfbits(mf);
        }
    }
    __syncthreads();

    // ---------------- conv2 phase: wave owns 2mt x 2nt ----------------
    int mt0 = (wv & 1) * 2;
    int nt0 = (wv >> 1) * 2;
    int abase[2];
    #pragma unroll
    for (int mi = 0; mi < 2; ++mi)
        abase[mi] = (24*(mt0+mi) + (ln>>3)*12 + (ln&7)) * XSTR;
    int aoff[20];
    #pragma unroll
    for (int c = 0; c < 20; ++c){
        int tap, inner;
        if (c < 13){ tap = 2*c + (quad>>1); inner = (quad&1)*8; }
        else       { tap = 4*(c-13) + quad; inner = 16; }
        int pt = 0;   // invalid taps -> pixel 0 (weights are zero there)
        if (tap < 25){ int kh = tap/5, kw = tap-5*kh; pt = kh*12 + kw; }
        aoff[c] = pt*XSTR + inner;
    }

    float sc2d = ws[0];
    const ushort_t* bsrc0 = w2bt + (size_t)(nt0*16 + ln)*32 + quad*8;
    const ushort_t* bsrc1 = bsrc0 + 16*32;

    floatx4 acc[2][2];
    #pragma unroll
    for (int mi = 0; mi < 2; ++mi)
        #pragma unroll
        for (int ni = 0; ni < 2; ++ni) acc[mi][ni] = (floatx4){0.f,0.f,0.f,0.f};

    #pragma unroll
    for (int c = 0; c < 20; ++c){
        ushort8 b0w = *(const ushort8*)(bsrc0 + c*2048);
        ushort8 b1w = *(const ushort8*)(bsrc1 + c*2048);
        ushort8 a0w = *(const ushort8*)(xs + abase[0] + aoff[c]);
        ushort8 a1w = *(const ushort8*)(xs + abase[1] + aoff[c]);
        bf16x8 a0 = __builtin_bit_cast(bf16x8, a0w);
        bf16x8 a1 = __builtin_bit_cast(bf16x8, a1w);
        bf16x8 b0 = __builtin_bit_cast(bf16x8, b0w);
        bf16x8 b1 = __builtin_bit_cast(bf16x8, b1w);
        acc[0][0] = __builtin_amdgcn_mfma_f32_16x16x32_bf16(a0, b0, acc[0][0], 0, 0, 0);
        acc[0][1] = __builtin_amdgcn_mfma_f32_16x16x32_bf16(a0, b1, acc[0][1], 0, 0, 0);
        acc[1][0] = __builtin_amdgcn_mfma_f32_16x16x32_bf16(a1, b0, acc[1][0], 0, 0, 0);
        acc[1][1] = __builtin_amdgcn_mfma_f32_16x16x32_bf16(a1, b1, acc[1][1], 0, 0, 0);
    }

    #pragma unroll
    for (int ni = 0; ni < 2; ++ni){
        int co = (nt0 + ni)*16 + ln;
        float bias2d = (co < 50) ? ws[OFF_B2 + co] : 0.0f;
        #pragma unroll
        for (int mi = 0; mi < 2; ++mi){
            int mt = mt0 + mi;
            float y0 = fmaf(acc[mi][ni][0], sc2d, bias2d);
            float y1 = fmaf(acc[mi][ni][1], sc2d, bias2d);
            float y2 = fmaf(acc[mi][ni][2], sc2d, bias2d);
            float y3 = fmaf(acc[mi][ni][3], sc2d, bias2d);
            float f0 = fmaxf(fmaxf(y0, y1), 0.0f);
            float f1 = fmaxf(fmaxf(y2, y3), 0.0f);
            float g0 = __shfl_xor(f0, 32);
            float g1 = __shfl_xor(f1, 32);
            float v0f = fmaxf(f0, g0), v1f = fmaxf(f1, g1);
            if (__ballot(fmaxf(v0f, v1f) >= 255.5f)){
                // exact mod-256 wrap path (rare); wave-uniform so both shfl partners enter
                unsigned int q0 = ((unsigned int)rintf(fmaxf(y0,0.f))) & 255u;
                unsigned int q1 = ((unsigned int)rintf(fmaxf(y1,0.f))) & 255u;
                unsigned int qq2 = ((unsigned int)rintf(fmaxf(y2,0.f))) & 255u;
                unsigned int q3 = ((unsigned int)rintf(fmaxf(y3,0.f))) & 255u;
                unsigned int h0 = q0 > q1 ? q0 : q1;
                unsigned int h1 = qq2 > q3 ? qq2 : q3;
                unsigned int p0 = (unsigned int)__shfl_xor((int)h0, 32);
                unsigned int p1 = (unsigned int)__shfl_xor((int)h1, 32);
                v0f = (float)(h0 > p0 ? h0 : p0);
                v1f = (float)(h1 > p1 ? h1 : p1);
            } else {
                v0f = rintf(v0f); v1f = rintf(v1f);
            }
            if (quad < 2 && co < 50){
                size_t base = (size_t)b*800 + co*16 + mt*4 + quad*2;
                q2bf[base]     = bfbits(v0f);
                q2bf[base + 1] = bfbits(v1f);
            }
        }
    }
}

// Fused fc1+fc2+log_softmax: block = 16 batch rows x 128 cols (1 of NCG=4 column
// groups), 256 threads = 4 waves x 2 n-tiles. Grid (B/16)*NCG = 1024 blocks.
// Each block writes its fc2 partial to part[cg][B][10], then threadfence+ticket;
// the LAST of the 4 group blocks sums the partials + bias and does log_softmax
// (removes the separate k_softmax launch). Tickets zeroed by k_conv12.
__global__ __launch_bounds__(256) void k_fc12(const ushort_t* q2bf, const ushort_t* w3bf,
                                              const float* ws, const float* w2,
                                              const float* b2, float* part, float* out,
                                              int* tick, int B){
    __shared__ float red[4*16*10];    // [wv][row16][c10]
    __shared__ int sLast;
    int tid = threadIdx.x;
    int lane = tid & 63, wv = tid >> 6;    // wv in [0,4)
    int ln = lane & 15, quad = lane >> 4;
    int bi = blockIdx.x;
    int cg = bi & (NCG-1);
    int gi = bi >> 2;                  // batch-group index in [0, B/16)
    int b0 = gi * 16;
    int n0 = cg*128 + wv*32;

    const ushort_t* asrc = q2bf + (size_t)(b0 + ln)*800 + quad*8;
    const ushort_t* bsrc0 = w3bf + (size_t)(n0 + ln)*800 + quad*8;
    const ushort_t* bsrc1 = bsrc0 + 16*800;

    floatx4 acc[2];
    acc[0] = (floatx4){0.f,0.f,0.f,0.f};
    acc[1] = (floatx4){0.f,0.f,0.f,0.f};

    ushort8 aw  = *(const ushort8*)(asrc);
    ushort8 b0w = *(const ushort8*)(bsrc0);
    ushort8 b1w = *(const ushort8*)(bsrc1);
    #pragma unroll
    for (int c = 0; c < 25; ++c){
        ushort8 aN, b0N, b1N;
        if (c < 24){
            aN  = *(const ushort8*)(asrc  + (c+1)*32);
            b0N = *(const ushort8*)(bsrc0 + (c+1)*32);
            b1N = *(const ushort8*)(bsrc1 + (c+1)*32);
        }
        acc[0] = __builtin_amdgcn_mfma_f32_16x16x32_bf16(
                     __builtin_bit_cast(bf16x8, aw), __builtin_bit_cast(bf16x8, b0w),
                     acc[0], 0, 0, 0);
        acc[1] = __builtin_amdgcn_mfma_f32_16x16x32_bf16(
                     __builtin_bit_cast(bf16x8, aw), __builtin_bit_cast(bf16x8, b1w),
                     acc[1], 0, 0, 0);
        aw = aN; b0w = b0N; b1w = b1N;
    }

    // quantize q3 in-register (bit-identical (uint)rintf&255 then S_N3*q)
    float sc3d = ws[1];
    float xf[4][2];
    #pragma unroll
    for (int t = 0; t < 2; ++t){
        int col = n0 + t*16 + ln;
        float bias = (col < 500) ? ws[OFF_B3 + col] : 0.0f;
        #pragma unroll
        for (int r = 0; r < 4; ++r){
            float y = fmaxf(fmaf(acc[t][r], sc3d, bias), 0.0f);
            unsigned int q = ((unsigned int)rintf(y)) & 255u;
            xf[r][t] = (col < 500) ? S_N3 * (float)q : 0.0f;
        }
    }

    // fc2 partials: per class c, 16-lane butterfly within quad group, wave-leader -> LDS
    #pragma unroll
    for (int c = 0; c < 10; ++c){
        float p[4] = {0.f, 0.f, 0.f, 0.f};
        #pragma unroll
        for (int t = 0; t < 2; ++t){
            int col = n0 + t*16 + ln;
            float w = (col < 500) ? w2[c*500 + col] : 0.0f;
            #pragma unroll
            for (int r = 0; r < 4; ++r) p[r] = fmaf(xf[r][t], w, p[r]);
        }
        #pragma unroll
        for (int m = 1; m <= 8; m <<= 1)
            #pragma unroll
            for (int r = 0; r < 4; ++r) p[r] += __shfl_xor(p[r], m);
        if (ln == 0){
            #pragma unroll
            for (int r = 0; r < 4; ++r)
                red[(wv*16 + quad*4 + r)*10 + c] = p[r];
        }
    }
    __syncthreads();

    if (tid < 160){
        int row = tid / 10, c = tid - 10*(tid/10);
        float s = red[row*10 + c] + red[160 + row*10 + c]
                + red[320 + row*10 + c] + red[480 + row*10 + c];
        part[((size_t)cg*B + b0 + row)*10 + c] = s;
    }

    // ticket: last of the 4 column-group blocks does the softmax for rows b0..b0+15
    __syncthreads();
    if (tid == 0){
        __threadfence();                       // release our part[] writes
        int old = atomicAdd(&tick[gi], 1);     // device-scope RMW
        sLast = (old == NCG - 1);
    }
    __syncthreads();
    if (sLast){
        __threadfence();                       // acquire side before reading others' parts
        if (tid < 16){
            int row = b0 + tid;
            const volatile float* pv = part;
            float lg[10], mx = -INFINITY;
            #pragma unroll
            for (int c = 0; c < 10; ++c){
                float s = b2[c];
                #pragma unroll
                for (int g = 0; g < NCG; ++g) s += pv[((size_t)g*B + row)*10 + c];
                lg[c] = s; mx = fmaxf(mx, s);
            }
            float sum = 0.0f;
            #pragma unroll
            for (int c = 0; c < 10; ++c) sum += expf(lg[c] - mx);
            float ls = logf(sum);
            #pragma unroll
            for (int c = 0; c < 10; ++c)
                out[(size_t)row*10 + c] = lg[c] - mx - ls;
        }
    }
}

extern "C" void kernel_launch(void* const* d_in, const int* in_sizes, int n_in,
                              void* d_out, int out_size, void* d_ws, size_t ws_size,
                              hipStream_t stream){
    const float* x   = (const float*)d_in[0];
    const float* c1w = (const float*)d_in[1];
    const float* c1b = (const float*)d_in[2];
    const float* c2w = (const float*)d_in[3];
    const float* c2b = (const float*)d_in[4];
    const float* f1w = (const float*)d_in[5];
    const float* f1b = (const float*)d_in[6];
    const float* f2w = (const float*)d_in[7];
    const float* f2b = (const float*)d_in[8];
    int B = in_sizes[0] / 784;

    float* ws = (float*)d_ws;
    float* pmn = ws + OFF_PMN;
    float* pmx = ws + OFF_PMX;
    int* tick = (int*)(ws + OFF_TICK);
    ushort_t* w1bf = (ushort_t*)((char*)d_ws + W1BF_BYTE);
    ushort_t* w2bf = (ushort_t*)((char*)d_ws + W2BF_BYTE);
    ushort_t* w3bf = (ushort_t*)((char*)d_ws + W3BF_BYTE);
    float* part = (float*)((char*)d_ws + PART_BYTE);
    ushort_t* q2bf = (ushort_t*)((char*)d_ws + Q2_BYTE);
    float* out = (float*)d_out;

    k_minmax<<<72, TPB, 0, stream>>>(c1w, c1b, c2w, c2b, f1w, f1b, pmn, pmx);
    k_make_eff<<<(N_EFF + TPB - 1)/TPB, TPB, 0, stream>>>(c1w, c1b, c2w, c2b, f1w, f1b, pmn, pmx, ws, w1bf, w2bf, w3bf);
    k_conv12<<<B, TPB, 0, stream>>>(x, w1bf, w2bf, ws, q2bf, tick, B);
    k_fc12<<<(B/16)*NCG, 256, 0, stream>>>(q2bf, w3bf, ws, f2w, f2b, part, out, tick, B);
}

// Round 5
// 167.012 us; speedup vs baseline: 1.3959x; 1.3959x over previous
//
#include <hip/hip_runtime.h>
#include <cmath>

#define TPB 256
typedef float floatx4 __attribute__((ext_vector_type(4)));
typedef __bf16 bf16x8 __attribute__((ext_vector_type(8)));
typedef unsigned short ushort8 __attribute__((ext_vector_type(8)));
typedef unsigned int uint2v __attribute__((ext_vector_type(2)));
typedef unsigned short ushort_t;

// ---------- workspace layout (float units) ----------
// [0]=sc2d ((S_N1*s_w2)/S_N2), [1]=sc3d ((S_N2*s_w3)/S_N3), [2]=K1 ((S_X1*s_w1)/S_N1)
// [16..88) = pmn[72] partial mins, [96..168) = pmx[72] partial maxes
#define OFF_PMN 16
#define OFF_PMX 96
#define OFF_B1 520       // 20  f32  (pre-divided by S_N1)
#define OFF_B2 544       // 50  f32  (pre-divided by S_N2)
#define OFF_B3 600       // 500 f32  (pre-divided by S_N3)
#define W1BF_BYTE 6144       // [32][32] u16 int weights (conv1)
#define W2BF_BYTE 8192       // [20 chunks][64 co][32 k] u16 int weights (conv2), 81920 B
#define W3BF_BYTE 131072     // [512][800]  u16 int weights (fc1)
#define PART_BYTE 1048576    // [8][B][10] f32 fc2 partial logits (1.31 MB; q2 at 29.4 MB)
#define Q2_BYTE  29360128ULL // [B][800] bf16 (6.6 MB)

#define S_X1 (3.5f/255.0f)
#define ZP_X1 36.0f
#define S_N1 (6.0f/255.0f)
#define S_N2 (8.0f/255.0f)
#define S_N3 (10.0f/255.0f)

// LDS pixel stride for conv2 A-reads: 40 u16 = 80 B = 20 banks (period-32 -> conflict-free)
#define XSTR 40
#define NCG 8   // fc1/fc2 column groups (each block covers 64 of 512 cols)

__device__ inline float qclip(float x, float s, float zp){
    return rintf(fminf(fmaxf(zp + x / s, 0.0f), 255.0f));
}
// exact bf16 bits for integer-valued floats |v| < 256
__device__ inline ushort_t bfbits(float v){
    return (ushort_t)(__float_as_uint(v) >> 16);
}

// per-block min/max partials; block->tensor map: 0:c1w 1:c1b 2-5:c2w 6:c2b 7-70:f1w 71:f1b
__global__ __launch_bounds__(TPB) void k_minmax(
        const float* c1w, const float* c1b, const float* c2w, const float* c2b,
        const float* f1w, const float* f1b, float* pmn, float* pmx){
    __shared__ float smn[TPB], smx[TPB];
    int bb = blockIdx.x, tid = threadIdx.x;
    const float* src; int n, sub, nsub;
    if      (bb == 0){ src=c1w; n=500;    sub=0;     nsub=1;  }
    else if (bb == 1){ src=c1b; n=20;     sub=0;     nsub=1;  }
    else if (bb <  6){ src=c2w; n=25000;  sub=bb-2;  nsub=4;  }
    else if (bb == 6){ src=c2b; n=50;     sub=0;     nsub=1;  }
    else if (bb < 71){ src=f1w; n=400000; sub=bb-7;  nsub=64; }
    else             { src=f1b; n=500;    sub=0;     nsub=1;  }
    float mn = INFINITY, mx = -INFINITY;
    for (int i = sub*TPB + tid; i < n; i += nsub*TPB){
        float v = src[i]; mn = fminf(mn, v); mx = fmaxf(mx, v);
    }
    smn[tid] = mn; smx[tid] = mx; __syncthreads();
    for (int s = TPB/2; s > 0; s >>= 1){
        if (tid < s){
            smn[tid] = fminf(smn[tid], smn[tid+s]);
            smx[tid] = fmaxf(smx[tid], smx[tid+s]);
        }
        __syncthreads();
    }
    if (tid == 0){ pmn[bb] = smn[0]; pmx[bb] = smx[0]; }
}

// w2bt chunk packing (20 chunks of K=32):
//   main c in 0..12:   oct q -> tap = 2c + (q>>1), ci = (q&1)*8 + jj   (tap 25 -> zero)
//   residue c in 13..19: oct q -> tap = 4(c-13) + q, ci = 16 + jj (jj<4; jj>=4 -> zero)
#define N_EFF 452157
__global__ __launch_bounds__(TPB) void k_make_eff(
        const float* c1w, const float* c1b, const float* c2w, const float* c2b,
        const float* f1w, const float* f1b, const float* pmn, const float* pmx,
        float* ws, ushort_t* w1bf, ushort_t* w2bf, ushort_t* w3bf){
    __shared__ float sS[6], sZ[6];
    int tid = threadIdx.x;
    int wv = tid >> 6, lane = tid & 63;
    const int starts[6] = {0,1,2,6,7,71};
    const int counts[6] = {1,1,4,1,64,1};
    #pragma unroll
    for (int rep = 0; rep < 2; ++rep){
        int t = wv + rep*4;
        if (t < 6){
            float mn = INFINITY, mx = -INFINITY;
            if (lane < counts[t]){ mn = pmn[starts[t]+lane]; mx = pmx[starts[t]+lane]; }
            #pragma unroll
            for (int off = 32; off > 0; off >>= 1){
                mn = fminf(mn, __shfl_xor(mn, off));
                mx = fmaxf(mx, __shfl_xor(mx, off));
            }
            if (lane == 0){
                float s = (mx - mn) / 255.0f;
                sS[t] = s;
                sZ[t] = truncf(fminf(fmaxf(0.0f - mn / s, 0.0f), 255.0f));
            }
        }
    }
    __syncthreads();

    int i = blockIdx.x * TPB + tid;
    if (i >= N_EFF) return;
    if (i < 1024){                   // w1bf: [n(32)][k(32)] integer weights
        int n = i >> 5, k = i & 31;
        float v = 0.0f;
        if (n < 20 && k < 25) v = qclip(c1w[n*25 + k], sS[0], sZ[0]) - sZ[0];
        w1bf[i] = bfbits(v);
    } else if (i < 1044){            // b1 pre-divided by S_N1
        int j = i - 1024;
        ws[OFF_B1 + j] = (sS[1] * (qclip(c1b[j], sS[1], sZ[1]) + sZ[1])) / S_N1;
    } else if (i < 42004){           // w2bt chunk-packed
        int j = i - 1044;
        int c = j >> 11, r = j & 2047, co = r >> 5, k = r & 31;
        int q = k >> 3, jj = k & 7;
        int tap, ci; bool valid;
        if (c < 13){ tap = 2*c + (q>>1); ci = (q&1)*8 + jj; valid = (tap < 25); }
        else       { tap = 4*(c-13) + q; ci = 16 + jj;      valid = (tap < 25) && (jj < 4); }
        valid = valid && (co < 50);
        float v = 0.0f;
        if (valid) v = qclip(c2w[(co*20 + ci)*25 + tap], sS[2], sZ[2]) - sZ[2];
        w2bf[j] = bfbits(v);
    } else if (i < 42054){           // b2 pre-divided by S_N2
        int j = i - 42004;
        ws[OFF_B2 + j] = (sS[3] * (qclip(c2b[j], sS[3], sZ[3]) + sZ[3])) / S_N2;
    } else if (i < 451654){          // w3bf: [n(512)][k(800)]
        int j = i - 42054;
        int n = j / 800, k = j - 800*n;
        float v = 0.0f;
        if (n < 500) v = qclip(f1w[n*800 + k], sS[4], sZ[4]) - sZ[4];
        w3bf[j] = bfbits(v);
    } else if (i < 452154){          // b3 pre-divided by S_N3
        int j = i - 451654;
        ws[OFF_B3 + j] = (sS[5] * (qclip(f1b[j], sS[5], sZ[5]) + sZ[5])) / S_N3;
    } else if (i == 452154){
        ws[0] = (S_N1 * sS[2]) / S_N2;   // conv2 combined scale, pre-divided
    } else if (i == 452155){
        ws[1] = (S_N2 * sS[4]) / S_N3;   // fc1 combined scale, pre-divided
    } else {
        ws[2] = (S_X1 * sS[0]) / S_N1;   // conv1 combined scale, pre-divided
    }
}

// Fused conv1+conv2, one image per block. (R2-measured 52 µs version.)
__global__ __launch_bounds__(TPB, 4) void k_conv12(const float* x, const ushort_t* w1bf,
                                                   const ushort_t* w2bt, const float* ws,
                                                   ushort_t* q2bf, int B){
    __shared__ __align__(16) ushort_t xs[144*XSTR];   // conv2 input, [pool pixel][ci(XSTR)]
    __shared__ __align__(16) ushort_t xim[3136];      // 4 per-quad copies of quantized image
    int b = blockIdx.x, tid = threadIdx.x;
    int lane = tid & 63, wv = tid >> 6;
    int ln = lane & 15, quad = lane >> 4;

    // zero xs pad columns 20-23 once (ci 24-39 are never read)
    for (int i = tid; i < 144; i += TPB){
        *(unsigned int*)(xs + i*XSTR + 20) = 0u;
        *(unsigned int*)(xs + i*XSTR + 22) = 0u;
    }

    // ---------------- conv1 phase ----------------
    // 784 px = 196 float4 loads; each thread quantizes 4 px, packs 2x u32, writes one
    // b64 per xim copy (byte offsets: copies at 1568*c, 1568%8==0; tid*8 aligned).
    const float* xb = x + (size_t)b * 784;
    if (tid < 196){
        floatx4 v = *(const floatx4*)(xb + tid*4);
        unsigned int qp[2];
        #pragma unroll
        for (int h = 0; h < 2; ++h){
            float q0 = rintf(fminf(fmaxf(ZP_X1 + v[2*h]   / S_X1, 0.0f), 255.0f)) - ZP_X1;
            float q1 = rintf(fminf(fmaxf(ZP_X1 + v[2*h+1] / S_X1, 0.0f), 255.0f)) - ZP_X1;
            qp[h] = (unsigned int)bfbits(q0) | ((unsigned int)bfbits(q1) << 16);
        }
        uint2v qq; qq.x = qp[0]; qq.y = qp[1];
        uint2v* dst = (uint2v*)xim;
        dst[tid]       = qq;
        dst[196 + tid] = qq;
        dst[392 + tid] = qq;
        dst[588 + tid] = qq;
    }

    int offj[8];
    #pragma unroll
    for (int j = 0; j < 8; ++j){
        int k = quad*8 + j;
        int kh = k / 5, kw = k - 5*kh;
        offj[j] = (k < 25) ? (kh*28 + kw) : 0;   // invalid taps read pixel 'base' (wt=0)
    }
    const ushort_t* xq = xim + quad*784;   // this quad's private copy

    ushort8 bw0 = *(const ushort8*)(w1bf + ln*32 + quad*8);
    ushort8 bw1 = *(const ushort8*)(w1bf + (16 + ln)*32 + quad*8);
    bf16x8 bf0 = __builtin_bit_cast(bf16x8, bw0);
    bf16x8 bf1 = __builtin_bit_cast(bf16x8, bw1);

    float K1 = ws[2];
    float B1_0 = ws[OFF_B1 + ln];
    float B1_1 = (ln < 4) ? ws[OFF_B1 + 16 + ln] : 0.0f;
    __syncthreads();

    #pragma unroll 3
    for (int i = 0; i < 9; ++i){
        int mt = 9*wv + i;
        int m = mt*16 + ln;
        int p = m >> 2, crn = m & 3;
        int ph_ = p / 12, pw_ = p - 12*ph_;
        int oh = 2*ph_ + (crn >> 1), ow = 2*pw_ + (crn & 1);
        int base = oh*28 + ow;
        ushort8 aw;
        #pragma unroll
        for (int j = 0; j < 8; ++j)
            aw[j] = xq[base + offj[j]];
        bf16x8 af = __builtin_bit_cast(bf16x8, aw);
        floatx4 z = (floatx4){0.f,0.f,0.f,0.f};
        floatx4 a0 = __builtin_amdgcn_mfma_f32_16x16x32_bf16(af, bf0, z, 0, 0, 0);
        floatx4 a1 = __builtin_amdgcn_mfma_f32_16x16x32_bf16(af, bf1, z, 0, 0, 0);

        int pp = mt*4 + quad;
        {
            float y0 = fmaf(a0[0], K1, B1_0), y1 = fmaf(a0[1], K1, B1_0);
            float y2 = fmaf(a0[2], K1, B1_0), y3 = fmaf(a0[3], K1, B1_0);
            float mA = fmaxf(fmaxf(y0, y1), y2);
            float mf = fmaxf(fmaxf(mA, y3), 0.0f);
            if (__ballot(mf >= 255.5f)){
                // exact mod-256 wrap path (rare)
                unsigned int q0 = ((unsigned int)rintf(fmaxf(y0,0.f))) & 255u;
                unsigned int q1 = ((unsigned int)rintf(fmaxf(y1,0.f))) & 255u;
                unsigned int qq2 = ((unsigned int)rintf(fmaxf(y2,0.f))) & 255u;
                unsigned int q3 = ((unsigned int)rintf(fmaxf(y3,0.f))) & 255u;
                unsigned int h0 = q0 > q1 ? q0 : q1;
                unsigned int h1 = qq2 > q3 ? qq2 : q3;
                mf = (float)(h0 > h1 ? h0 : h1);
            } else {
                mf = rintf(mf);
            }
            xs[pp*XSTR + ln] = bfbits(mf);
        }
        if (ln < 4){
            float y0 = fmaf(a1[0], K1, B1_1), y1 = fmaf(a1[1], K1, B1_1);
            float y2 = fmaf(a1[2], K1, B1_1), y3 = fmaf(a1[3], K1, B1_1);
            float mA = fmaxf(fmaxf(y0, y1), y2);
            float mf = fmaxf(fmaxf(mA, y3), 0.0f);
            if (__ballot(mf >= 255.5f)){
                unsigned int q0 = ((unsigned int)rintf(fmaxf(y0,0.f))) & 255u;
                unsigned int q1 = ((unsigned int)rintf(fmaxf(y1,0.f))) & 255u;
                unsigned int qq2 = ((unsigned int)rintf(fmaxf(y2,0.f))) & 255u;
                unsigned int q3 = ((unsigned int)rintf(fmaxf(y3,0.f))) & 255u;
                unsigned int h0 = q0 > q1 ? q0 : q1;
                unsigned int h1 = qq2 > q3 ? qq2 : q3;
                mf = (float)(h0 > h1 ? h0 : h1);
            } else {
                mf = rintf(mf);
            }
            xs[pp*XSTR + 16 + ln] = bfbits(mf);
        }
    }
    __syncthreads();

    // ---------------- conv2 phase: wave owns 2mt x 2nt ----------------
    int mt0 = (wv & 1) * 2;
    int nt0 = (wv >> 1) * 2;
    int abase[2];
    #pragma unroll
    for (int mi = 0; mi < 2; ++mi)
        abase[mi] = (24*(mt0+mi) + (ln>>3)*12 + (ln&7)) * XSTR;
    int aoff[20];
    #pragma unroll
    for (int c = 0; c < 20; ++c){
        int tap, inner;
        if (c < 13){ tap = 2*c + (quad>>1); inner = (quad&1)*8; }
        else       { tap = 4*(c-13) + quad; inner = 16; }
        int pt = 0;   // invalid taps -> pixel 0 (weights are zero there)
        if (tap < 25){ int kh = tap/5, kw = tap-5*kh; pt = kh*12 + kw; }
        aoff[c] = pt*XSTR + inner;
    }

    float sc2d = ws[0];
    const ushort_t* bsrc0 = w2bt + (size_t)(nt0*16 + ln)*32 + quad*8;
    const ushort_t* bsrc1 = bsrc0 + 16*32;

    floatx4 acc[2][2];
    #pragma unroll
    for (int mi = 0; mi < 2; ++mi)
        #pragma unroll
        for (int ni = 0; ni < 2; ++ni) acc[mi][ni] = (floatx4){0.f,0.f,0.f,0.f};

    #pragma unroll
    for (int c = 0; c < 20; ++c){
        ushort8 b0w = *(const ushort8*)(bsrc0 + c*2048);
        ushort8 b1w = *(const ushort8*)(bsrc1 + c*2048);
        ushort8 a0w = *(const ushort8*)(xs + abase[0] + aoff[c]);
        ushort8 a1w = *(const ushort8*)(xs + abase[1] + aoff[c]);
        bf16x8 a0 = __builtin_bit_cast(bf16x8, a0w);
        bf16x8 a1 = __builtin_bit_cast(bf16x8, a1w);
        bf16x8 b0 = __builtin_bit_cast(bf16x8, b0w);
        bf16x8 b1 = __builtin_bit_cast(bf16x8, b1w);
        acc[0][0] = __builtin_amdgcn_mfma_f32_16x16x32_bf16(a0, b0, acc[0][0], 0, 0, 0);
        acc[0][1] = __builtin_amdgcn_mfma_f32_16x16x32_bf16(a0, b1, acc[0][1], 0, 0, 0);
        acc[1][0] = __builtin_amdgcn_mfma_f32_16x16x32_bf16(a1, b0, acc[1][0], 0, 0, 0);
        acc[1][1] = __builtin_amdgcn_mfma_f32_16x16x32_bf16(a1, b1, acc[1][1], 0, 0, 0);
    }

    #pragma unroll
    for (int ni = 0; ni < 2; ++ni){
        int co = (nt0 + ni)*16 + ln;
        float bias2d = (co < 50) ? ws[OFF_B2 + co] : 0.0f;
        #pragma unroll
        for (int mi = 0; mi < 2; ++mi){
            int mt = mt0 + mi;
            float y0 = fmaf(acc[mi][ni][0], sc2d, bias2d);
            float y1 = fmaf(acc[mi][ni][1], sc2d, bias2d);
            float y2 = fmaf(acc[mi][ni][2], sc2d, bias2d);
            float y3 = fmaf(acc[mi][ni][3], sc2d, bias2d);
            float f0 = fmaxf(fmaxf(y0, y1), 0.0f);
            float f1 = fmaxf(fmaxf(y2, y3), 0.0f);
            float g0 = __shfl_xor(f0, 32);
            float g1 = __shfl_xor(f1, 32);
            float v0f = fmaxf(f0, g0), v1f = fmaxf(f1, g1);
            if (__ballot(fmaxf(v0f, v1f) >= 255.5f)){
                // exact mod-256 wrap path (rare); wave-uniform so both shfl partners enter
                unsigned int q0 = ((unsigned int)rintf(fmaxf(y0,0.f))) & 255u;
                unsigned int q1 = ((unsigned int)rintf(fmaxf(y1,0.f))) & 255u;
                unsigned int qq2 = ((unsigned int)rintf(fmaxf(y2,0.f))) & 255u;
                unsigned int q3 = ((unsigned int)rintf(fmaxf(y3,0.f))) & 255u;
                unsigned int h0 = q0 > q1 ? q0 : q1;
                unsigned int h1 = qq2 > q3 ? qq2 : q3;
                unsigned int p0 = (unsigned int)__shfl_xor((int)h0, 32);
                unsigned int p1 = (unsigned int)__shfl_xor((int)h1, 32);
                v0f = (float)(h0 > p0 ? h0 : p0);
                v1f = (float)(h1 > p1 ? h1 : p1);
            } else {
                v0f = rintf(v0f); v1f = rintf(v1f);
            }
            if (quad < 2 && co < 50){
                size_t base = (size_t)b*800 + co*16 + mt*4 + quad*2;
                q2bf[base]     = bfbits(v0f);
                q2bf[base + 1] = bfbits(v1f);
            }
        }
    }
}

// Fused fc1+fc2: R19 — block = 16 batch rows x 64 cols (1 of NCG=8 groups),
// 256 threads = 4 waves x 1 n-tile each. Grid (B/16)*8 = 2048 blocks -> 8 blocks/CU
// -> 32 waves/CU (8/SIMD) to hide the L2 weight-stream latency (R4 subtraction put
// the NCG=4 version at ~45 µs, ~5x its ~9 µs L1/L2-BW floor -> latency-bound at
// 4 waves/SIMD). Depth-1 prefetch kept. Partials to part[cg][B][10]; k_softmax sums.
__global__ __launch_bounds__(256) void k_fc12(const ushort_t* q2bf, const ushort_t* w3bf,
                                              const float* ws, const float* w2,
                                              float* part, int B){
    __shared__ float red[4*16*10];    // [wv][row16][c10]
    int tid = threadIdx.x;
    int lane = tid & 63, wv = tid >> 6;    // wv in [0,4)
    int ln = lane & 15, quad = lane >> 4;
    int bi = blockIdx.x;
    int cg = bi & (NCG-1);
    int b0 = (bi >> 3) * 16;
    int n0 = cg*64 + wv*16;

    const ushort_t* asrc = q2bf + (size_t)(b0 + ln)*800 + quad*8;
    const ushort_t* bsrc = w3bf + (size_t)(n0 + ln)*800 + quad*8;

    floatx4 acc = (floatx4){0.f,0.f,0.f,0.f};

    ushort8 aw = *(const ushort8*)(asrc);
    ushort8 bw = *(const ushort8*)(bsrc);
    #pragma unroll
    for (int c = 0; c < 25; ++c){
        ushort8 aN, bN;
        if (c < 24){
            aN = *(const ushort8*)(asrc + (c+1)*32);
            bN = *(const ushort8*)(bsrc + (c+1)*32);
        }
        acc = __builtin_amdgcn_mfma_f32_16x16x32_bf16(
                  __builtin_bit_cast(bf16x8, aw), __builtin_bit_cast(bf16x8, bw),
                  acc, 0, 0, 0);
        aw = aN; bw = bN;
    }

    // quantize q3 in-register (bit-identical (uint)rintf&255 then S_N3*q)
    float sc3d = ws[1];
    int col = n0 + ln;
    float bias = (col < 500) ? ws[OFF_B3 + col] : 0.0f;
    float xf[4];
    #pragma unroll
    for (int r = 0; r < 4; ++r){
        float y = fmaxf(fmaf(acc[r], sc3d, bias), 0.0f);
        unsigned int q = ((unsigned int)rintf(y)) & 255u;
        xf[r] = (col < 500) ? S_N3 * (float)q : 0.0f;
    }

    // fc2 partials: per class c, 16-lane butterfly within quad group, wave-leader -> LDS
    #pragma unroll
    for (int c = 0; c < 10; ++c){
        float w = (col < 500) ? w2[c*500 + col] : 0.0f;
        float p[4];
        #pragma unroll
        for (int r = 0; r < 4; ++r) p[r] = xf[r] * w;
        #pragma unroll
        for (int m = 1; m <= 8; m <<= 1)
            #pragma unroll
            for (int r = 0; r < 4; ++r) p[r] += __shfl_xor(p[r], m);
        if (ln == 0){
            #pragma unroll
            for (int r = 0; r < 4; ++r)
                red[(wv*16 + quad*4 + r)*10 + c] = p[r];
        }
    }
    __syncthreads();

    if (tid < 160){
        int row = tid / 10, c = tid - 10*(tid/10);
        float s = red[row*10 + c] + red[160 + row*10 + c]
                + red[320 + row*10 + c] + red[480 + row*10 + c];
        part[((size_t)cg*B + b0 + row)*10 + c] = s;
    }
}

// sum NCG column-group partials + bias, log_softmax per row
__global__ __launch_bounds__(256) void k_softmax(const float* part, const float* b2,
                                                 float* out, int B){
    int i = blockIdx.x*256 + threadIdx.x;
    if (i >= B) return;
    float lg[10], mx = -INFINITY;
    #pragma unroll
    for (int c = 0; c < 10; ++c){
        float s = b2[c];
        #pragma unroll
        for (int g = 0; g < NCG; ++g) s += part[((size_t)g*B + i)*10 + c];
        lg[c] = s; mx = fmaxf(mx, s);
    }
    float sum = 0.0f;
    #pragma unroll
    for (int c = 0; c < 10; ++c) sum += expf(lg[c] - mx);
    float ls = logf(sum);
    #pragma unroll
    for (int c = 0; c < 10; ++c)
        out[(size_t)i*10 + c] = lg[c] - mx - ls;
}

extern "C" void kernel_launch(void* const* d_in, const int* in_sizes, int n_in,
                              void* d_out, int out_size, void* d_ws, size_t ws_size,
                              hipStream_t stream){
    const float* x   = (const float*)d_in[0];
    const float* c1w = (const float*)d_in[1];
    const float* c1b = (const float*)d_in[2];
    const float* c2w = (const float*)d_in[3];
    const float* c2b = (const float*)d_in[4];
    const float* f1w = (const float*)d_in[5];
    const float* f1b = (const float*)d_in[6];
    const float* f2w = (const float*)d_in[7];
    const float* f2b = (const float*)d_in[8];
    int B = in_sizes[0] / 784;

    float* ws = (float*)d_ws;
    float* pmn = ws + OFF_PMN;
    float* pmx = ws + OFF_PMX;
    ushort_t* w1bf = (ushort_t*)((char*)d_ws + W1BF_BYTE);
    ushort_t* w2bf = (ushort_t*)((char*)d_ws + W2BF_BYTE);
    ushort_t* w3bf = (ushort_t*)((char*)d_ws + W3BF_BYTE);
    float* part = (float*)((char*)d_ws + PART_BYTE);
    ushort_t* q2bf = (ushort_t*)((char*)d_ws + Q2_BYTE);
    float* out = (float*)d_out;

    k_minmax<<<72, TPB, 0, stream>>>(c1w, c1b, c2w, c2b, f1w, f1b, pmn, pmx);
    k_make_eff<<<(N_EFF + TPB - 1)/TPB, TPB, 0, stream>>>(c1w, c1b, c2w, c2b, f1w, f1b, pmn, pmx, ws, w1bf, w2bf, w3bf);
    k_conv12<<<B, TPB, 0, stream>>>(x, w1bf, w2bf, ws, q2bf, B);
    k_fc12<<<(B/16)*NCG, 256, 0, stream>>>(q2bf, w3bf, ws, f2w, part, B);
    k_softmax<<<(B + 255)/256, 256, 0, stream>>>(part, f2b, out, B);
}

// Round 6
// 154.277 us; speedup vs baseline: 1.5112x; 1.0826x over previous
//
#include <hip/hip_runtime.h>
#include <cmath>

#define TPB 256
typedef float floatx4 __attribute__((ext_vector_type(4)));
typedef __bf16 bf16x8 __attribute__((ext_vector_type(8)));
typedef unsigned short ushort8 __attribute__((ext_vector_type(8)));
typedef unsigned int uint2v __attribute__((ext_vector_type(2)));
typedef unsigned short ushort_t;

// ---------- workspace layout (float units) ----------
// [0]=sc2d ((S_N1*s_w2)/S_N2), [1]=sc3d ((S_N2*s_w3)/S_N3), [2]=K1 ((S_X1*s_w1)/S_N1)
// [16..88) = pmn[72] partial mins, [96..168) = pmx[72] partial maxes
#define OFF_PMN 16
#define OFF_PMX 96
#define OFF_B1 520       // 20  f32  (pre-divided by S_N1)
#define OFF_B2 544       // 50  f32  (pre-divided by S_N2)
#define OFF_B3 600       // 500 f32  (pre-divided by S_N3)
#define W1BF_BYTE 6144       // [32][32] u16 int weights (conv1)
#define W2BF_BYTE 8192       // [20 chunks][64 co][32 k] u16 int weights (conv2), 81920 B
#define W3BF_BYTE 131072     // w3t: [nt32][c25][ln16][k32] u16 (fc1), 819200 B
#define Q2_BYTE  29360128ULL // q2t: [B/16][c25][ln16][k32] bf16 (6.6 MB)

#define S_X1 (3.5f/255.0f)
#define ZP_X1 36.0f
#define S_N1 (6.0f/255.0f)
#define S_N2 (8.0f/255.0f)
#define S_N3 (10.0f/255.0f)

// LDS pixel stride for conv2 A-reads: 40 u16 = 80 B = 20 banks (period-32 -> conflict-free)
#define XSTR 40

__device__ inline float qclip(float x, float s, float zp){
    return rintf(fminf(fmaxf(zp + x / s, 0.0f), 255.0f));
}
// exact bf16 bits for integer-valued floats |v| < 256
__device__ inline ushort_t bfbits(float v){
    return (ushort_t)(__float_as_uint(v) >> 16);
}

// per-block min/max partials; block->tensor map: 0:c1w 1:c1b 2-5:c2w 6:c2b 7-70:f1w 71:f1b
__global__ __launch_bounds__(TPB) void k_minmax(
        const float* c1w, const float* c1b, const float* c2w, const float* c2b,
        const float* f1w, const float* f1b, float* pmn, float* pmx){
    __shared__ float smn[TPB], smx[TPB];
    int bb = blockIdx.x, tid = threadIdx.x;
    const float* src; int n, sub, nsub;
    if      (bb == 0){ src=c1w; n=500;    sub=0;     nsub=1;  }
    else if (bb == 1){ src=c1b; n=20;     sub=0;     nsub=1;  }
    else if (bb <  6){ src=c2w; n=25000;  sub=bb-2;  nsub=4;  }
    else if (bb == 6){ src=c2b; n=50;     sub=0;     nsub=1;  }
    else if (bb < 71){ src=f1w; n=400000; sub=bb-7;  nsub=64; }
    else             { src=f1b; n=500;    sub=0;     nsub=1;  }
    float mn = INFINITY, mx = -INFINITY;
    for (int i = sub*TPB + tid; i < n; i += nsub*TPB){
        float v = src[i]; mn = fminf(mn, v); mx = fmaxf(mx, v);
    }
    smn[tid] = mn; smx[tid] = mx; __syncthreads();
    for (int s = TPB/2; s > 0; s >>= 1){
        if (tid < s){
            smn[tid] = fminf(smn[tid], smn[tid+s]);
            smx[tid] = fmaxf(smx[tid], smx[tid+s]);
        }
        __syncthreads();
    }
    if (tid == 0){ pmn[bb] = smn[0]; pmx[bb] = smx[0]; }
}

// w2bt chunk packing (20 chunks of K=32):
//   main c in 0..12:   oct q -> tap = 2c + (q>>1), ci = (q&1)*8 + jj   (tap 25 -> zero)
//   residue c in 13..19: oct q -> tap = 4(c-13) + q, ci = 16 + jj (jj<4; jj>=4 -> zero)
#define N_EFF 452157
__global__ __launch_bounds__(TPB) void k_make_eff(
        const float* c1w, const float* c1b, const float* c2w, const float* c2b,
        const float* f1w, const float* f1b, const float* pmn, const float* pmx,
        float* ws, ushort_t* w1bf, ushort_t* w2bf, ushort_t* w3bf){
    __shared__ float sS[6], sZ[6];
    int tid = threadIdx.x;
    int wv = tid >> 6, lane = tid & 63;
    const int starts[6] = {0,1,2,6,7,71};
    const int counts[6] = {1,1,4,1,64,1};
    #pragma unroll
    for (int rep = 0; rep < 2; ++rep){
        int t = wv + rep*4;
        if (t < 6){
            float mn = INFINITY, mx = -INFINITY;
            if (lane < counts[t]){ mn = pmn[starts[t]+lane]; mx = pmx[starts[t]+lane]; }
            #pragma unroll
            for (int off = 32; off > 0; off >>= 1){
                mn = fminf(mn, __shfl_xor(mn, off));
                mx = fmaxf(mx, __shfl_xor(mx, off));
            }
            if (lane == 0){
                float s = (mx - mn) / 255.0f;
                sS[t] = s;
                sZ[t] = truncf(fminf(fmaxf(0.0f - mn / s, 0.0f), 255.0f));
            }
        }
    }
    __syncthreads();

    int i = blockIdx.x * TPB + tid;
    if (i >= N_EFF) return;
    if (i < 1024){                   // w1bf: [n(32)][k(32)] integer weights
        int n = i >> 5, k = i & 31;
        float v = 0.0f;
        if (n < 20 && k < 25) v = qclip(c1w[n*25 + k], sS[0], sZ[0]) - sZ[0];
        w1bf[i] = bfbits(v);
    } else if (i < 1044){            // b1 pre-divided by S_N1
        int j = i - 1024;
        ws[OFF_B1 + j] = (sS[1] * (qclip(c1b[j], sS[1], sZ[1]) + sZ[1])) / S_N1;
    } else if (i < 42004){           // w2bt chunk-packed
        int j = i - 1044;
        int c = j >> 11, r = j & 2047, co = r >> 5, k = r & 31;
        int q = k >> 3, jj = k & 7;
        int tap, ci; bool valid;
        if (c < 13){ tap = 2*c + (q>>1); ci = (q&1)*8 + jj; valid = (tap < 25); }
        else       { tap = 4*(c-13) + q; ci = 16 + jj;      valid = (tap < 25) && (jj < 4); }
        valid = valid && (co < 50);
        float v = 0.0f;
        if (valid) v = qclip(c2w[(co*20 + ci)*25 + tap], sS[2], sZ[2]) - sZ[2];
        w2bf[j] = bfbits(v);
    } else if (i < 42054){           // b2 pre-divided by S_N2
        int j = i - 42004;
        ws[OFF_B2 + j] = (sS[3] * (qclip(c2b[j], sS[3], sZ[3]) + sZ[3])) / S_N2;
    } else if (i < 451654){          // w3t: tiled [nt(32)][c(25)][ln(16)][k(32)]
        int j = i - 42054;
        int n = j / 800, k = j - 800*n;
        float v = 0.0f;
        if (n < 500) v = qclip(f1w[n*800 + k], sS[4], sZ[4]) - sZ[4];
        w3bf[(((n>>4)*25 + (k>>5))*16 + (n&15))*32 + (k&31)] = bfbits(v);
    } else if (i < 452154){          // b3 pre-divided by S_N3
        int j = i - 451654;
        ws[OFF_B3 + j] = (sS[5] * (qclip(f1b[j], sS[5], sZ[5]) + sZ[5])) / S_N3;
    } else if (i == 452154){
        ws[0] = (S_N1 * sS[2]) / S_N2;   // conv2 combined scale, pre-divided
    } else if (i == 452155){
        ws[1] = (S_N2 * sS[4]) / S_N3;   // fc1 combined scale, pre-divided
    } else {
        ws[2] = (S_X1 * sS[0]) / S_N1;   // conv1 combined scale, pre-divided
    }
}

// Fused conv1+conv2, one image per block. (R2-measured 52 µs version; only the q2
// write indices changed to the fc12-fragment tiled layout q2t[b/16][c][b%16][k&31].)
__global__ __launch_bounds__(TPB, 4) void k_conv12(const float* x, const ushort_t* w1bf,
                                                   const ushort_t* w2bt, const float* ws,
                                                   ushort_t* q2bf, int B){
    __shared__ __align__(16) ushort_t xs[144*XSTR];   // conv2 input, [pool pixel][ci(XSTR)]
    __shared__ __align__(16) ushort_t xim[3136];      // 4 per-quad copies of quantized image
    int b = blockIdx.x, tid = threadIdx.x;
    int lane = tid & 63, wv = tid >> 6;
    int ln = lane & 15, quad = lane >> 4;

    // zero xs pad columns 20-23 once (ci 24-39 are never read)
    for (int i = tid; i < 144; i += TPB){
        *(unsigned int*)(xs + i*XSTR + 20) = 0u;
        *(unsigned int*)(xs + i*XSTR + 22) = 0u;
    }

    // ---------------- conv1 phase ----------------
    // 784 px = 196 float4 loads; each thread quantizes 4 px, packs 2x u32, writes one
    // b64 per xim copy (byte offsets: copies at 1568*c, 1568%8==0; tid*8 aligned).
    const float* xb = x + (size_t)b * 784;
    if (tid < 196){
        floatx4 v = *(const floatx4*)(xb + tid*4);
        unsigned int qp[2];
        #pragma unroll
        for (int h = 0; h < 2; ++h){
            float q0 = rintf(fminf(fmaxf(ZP_X1 + v[2*h]   / S_X1, 0.0f), 255.0f)) - ZP_X1;
            float q1 = rintf(fminf(fmaxf(ZP_X1 + v[2*h+1] / S_X1, 0.0f), 255.0f)) - ZP_X1;
            qp[h] = (unsigned int)bfbits(q0) | ((unsigned int)bfbits(q1) << 16);
        }
        uint2v qq; qq.x = qp[0]; qq.y = qp[1];
        uint2v* dst = (uint2v*)xim;
        dst[tid]       = qq;
        dst[196 + tid] = qq;
        dst[392 + tid] = qq;
        dst[588 + tid] = qq;
    }

    int offj[8];
    #pragma unroll
    for (int j = 0; j < 8; ++j){
        int k = quad*8 + j;
        int kh = k / 5, kw = k - 5*kh;
        offj[j] = (k < 25) ? (kh*28 + kw) : 0;   // invalid taps read pixel 'base' (wt=0)
    }
    const ushort_t* xq = xim + quad*784;   // this quad's private copy

    ushort8 bw0 = *(const ushort8*)(w1bf + ln*32 + quad*8);
    ushort8 bw1 = *(const ushort8*)(w1bf + (16 + ln)*32 + quad*8);
    bf16x8 bf0 = __builtin_bit_cast(bf16x8, bw0);
    bf16x8 bf1 = __builtin_bit_cast(bf16x8, bw1);

    float K1 = ws[2];
    float B1_0 = ws[OFF_B1 + ln];
    float B1_1 = (ln < 4) ? ws[OFF_B1 + 16 + ln] : 0.0f;
    __syncthreads();

    #pragma unroll 3
    for (int i = 0; i < 9; ++i){
        int mt = 9*wv + i;
        int m = mt*16 + ln;
        int p = m >> 2, crn = m & 3;
        int ph_ = p / 12, pw_ = p - 12*ph_;
        int oh = 2*ph_ + (crn >> 1), ow = 2*pw_ + (crn & 1);
        int base = oh*28 + ow;
        ushort8 aw;
        #pragma unroll
        for (int j = 0; j < 8; ++j)
            aw[j] = xq[base + offj[j]];
        bf16x8 af = __builtin_bit_cast(bf16x8, aw);
        floatx4 z = (floatx4){0.f,0.f,0.f,0.f};
        floatx4 a0 = __builtin_amdgcn_mfma_f32_16x16x32_bf16(af, bf0, z, 0, 0, 0);
        floatx4 a1 = __builtin_amdgcn_mfma_f32_16x16x32_bf16(af, bf1, z, 0, 0, 0);

        int pp = mt*4 + quad;
        {
            float y0 = fmaf(a0[0], K1, B1_0), y1 = fmaf(a0[1], K1, B1_0);
            float y2 = fmaf(a0[2], K1, B1_0), y3 = fmaf(a0[3], K1, B1_0);
            float mA = fmaxf(fmaxf(y0, y1), y2);
            float mf = fmaxf(fmaxf(mA, y3), 0.0f);
            if (__ballot(mf >= 255.5f)){
                // exact mod-256 wrap path (rare)
                unsigned int q0 = ((unsigned int)rintf(fmaxf(y0,0.f))) & 255u;
                unsigned int q1 = ((unsigned int)rintf(fmaxf(y1,0.f))) & 255u;
                unsigned int qq2 = ((unsigned int)rintf(fmaxf(y2,0.f))) & 255u;
                unsigned int q3 = ((unsigned int)rintf(fmaxf(y3,0.f))) & 255u;
                unsigned int h0 = q0 > q1 ? q0 : q1;
                unsigned int h1 = qq2 > q3 ? qq2 : q3;
                mf = (float)(h0 > h1 ? h0 : h1);
            } else {
                mf = rintf(mf);
            }
            xs[pp*XSTR + ln] = bfbits(mf);
        }
        if (ln < 4){
            float y0 = fmaf(a1[0], K1, B1_1), y1 = fmaf(a1[1], K1, B1_1);
            float y2 = fmaf(a1[2], K1, B1_1), y3 = fmaf(a1[3], K1, B1_1);
            float mA = fmaxf(fmaxf(y0, y1), y2);
            float mf = fmaxf(fmaxf(mA, y3), 0.0f);
            if (__ballot(mf >= 255.5f)){
                unsigned int q0 = ((unsigned int)rintf(fmaxf(y0,0.f))) & 255u;
                unsigned int q1 = ((unsigned int)rintf(fmaxf(y1,0.f))) & 255u;
                unsigned int qq2 = ((unsigned int)rintf(fmaxf(y2,0.f))) & 255u;
                unsigned int q3 = ((unsigned int)rintf(fmaxf(y3,0.f))) & 255u;
                unsigned int h0 = q0 > q1 ? q0 : q1;
                unsigned int h1 = qq2 > q3 ? qq2 : q3;
                mf = (float)(h0 > h1 ? h0 : h1);
            } else {
                mf = rintf(mf);
            }
            xs[pp*XSTR + 16 + ln] = bfbits(mf);
        }
    }
    __syncthreads();

    // ---------------- conv2 phase: wave owns 2mt x 2nt ----------------
    int mt0 = (wv & 1) * 2;
    int nt0 = (wv >> 1) * 2;
    int abase[2];
    #pragma unroll
    for (int mi = 0; mi < 2; ++mi)
        abase[mi] = (24*(mt0+mi) + (ln>>3)*12 + (ln&7)) * XSTR;
    int aoff[20];
    #pragma unroll
    for (int c = 0; c < 20; ++c){
        int tap, inner;
        if (c < 13){ tap = 2*c + (quad>>1); inner = (quad&1)*8; }
        else       { tap = 4*(c-13) + quad; inner = 16; }
        int pt = 0;   // invalid taps -> pixel 0 (weights are zero there)
        if (tap < 25){ int kh = tap/5, kw = tap-5*kh; pt = kh*12 + kw; }
        aoff[c] = pt*XSTR + inner;
    }

    float sc2d = ws[0];
    const ushort_t* bsrc0 = w2bt + (size_t)(nt0*16 + ln)*32 + quad*8;
    const ushort_t* bsrc1 = bsrc0 + 16*32;

    floatx4 acc[2][2];
    #pragma unroll
    for (int mi = 0; mi < 2; ++mi)
        #pragma unroll
        for (int ni = 0; ni < 2; ++ni) acc[mi][ni] = (floatx4){0.f,0.f,0.f,0.f};

    #pragma unroll
    for (int c = 0; c < 20; ++c){
        ushort8 b0w = *(const ushort8*)(bsrc0 + c*2048);
        ushort8 b1w = *(const ushort8*)(bsrc1 + c*2048);
        ushort8 a0w = *(const ushort8*)(xs + abase[0] + aoff[c]);
        ushort8 a1w = *(const ushort8*)(xs + abase[1] + aoff[c]);
        bf16x8 a0 = __builtin_bit_cast(bf16x8, a0w);
        bf16x8 a1 = __builtin_bit_cast(bf16x8, a1w);
        bf16x8 b0 = __builtin_bit_cast(bf16x8, b0w);
        bf16x8 b1 = __builtin_bit_cast(bf16x8, b1w);
        acc[0][0] = __builtin_amdgcn_mfma_f32_16x16x32_bf16(a0, b0, acc[0][0], 0, 0, 0);
        acc[0][1] = __builtin_amdgcn_mfma_f32_16x16x32_bf16(a0, b1, acc[0][1], 0, 0, 0);
        acc[1][0] = __builtin_amdgcn_mfma_f32_16x16x32_bf16(a1, b0, acc[1][0], 0, 0, 0);
        acc[1][1] = __builtin_amdgcn_mfma_f32_16x16x32_bf16(a1, b1, acc[1][1], 0, 0, 0);
    }

    int bg = b >> 4, brow = b & 15;
    #pragma unroll
    for (int ni = 0; ni < 2; ++ni){
        int co = (nt0 + ni)*16 + ln;
        float bias2d = (co < 50) ? ws[OFF_B2 + co] : 0.0f;
        #pragma unroll
        for (int mi = 0; mi < 2; ++mi){
            int mt = mt0 + mi;
            float y0 = fmaf(acc[mi][ni][0], sc2d, bias2d);
            float y1 = fmaf(acc[mi][ni][1], sc2d, bias2d);
            float y2 = fmaf(acc[mi][ni][2], sc2d, bias2d);
            float y3 = fmaf(acc[mi][ni][3], sc2d, bias2d);
            float f0 = fmaxf(fmaxf(y0, y1), 0.0f);
            float f1 = fmaxf(fmaxf(y2, y3), 0.0f);
            float g0 = __shfl_xor(f0, 32);
            float g1 = __shfl_xor(f1, 32);
            float v0f = fmaxf(f0, g0), v1f = fmaxf(f1, g1);
            if (__ballot(fmaxf(v0f, v1f) >= 255.5f)){
                // exact mod-256 wrap path (rare); wave-uniform so both shfl partners enter
                unsigned int q0 = ((unsigned int)rintf(fmaxf(y0,0.f))) & 255u;
                unsigned int q1 = ((unsigned int)rintf(fmaxf(y1,0.f))) & 255u;
                unsigned int qq2 = ((unsigned int)rintf(fmaxf(y2,0.f))) & 255u;
                unsigned int q3 = ((unsigned int)rintf(fmaxf(y3,0.f))) & 255u;
                unsigned int h0 = q0 > q1 ? q0 : q1;
                unsigned int h1 = qq2 > q3 ? qq2 : q3;
                unsigned int p0 = (unsigned int)__shfl_xor((int)h0, 32);
                unsigned int p1 = (unsigned int)__shfl_xor((int)h1, 32);
                v0f = (float)(h0 > p0 ? h0 : p0);
                v1f = (float)(h1 > p1 ? h1 : p1);
            } else {
                v0f = rintf(v0f); v1f = rintf(v1f);
            }
            if (quad < 2 && co < 50){
                int k0 = co*16 + mt*4 + quad*2;           // flat fc1 K index (even)
                size_t off = ((size_t)bg*25 + (k0 >> 5))*512 + brow*32 + (k0 & 31);
                q2bf[off]     = bfbits(v0f);
                q2bf[off + 1] = bfbits(v1f);
            }
        }
    }
}

// Fused fc1+fc2+log_softmax (R0 structure + tiled coalesced layouts): block = 16 batch
// rows x all 512 cols, 512 threads = 8 waves x 4 n-tiles, grid B/16 = 256.
// A-fragment read: q2t[gi][c][ln][32] -> one dense 1KB block per wave per c (was
// 16-way 1600B-strided -> 16 cache lines per instr, the L1-throughput bottleneck).
// B-fragment read: w3t[nt][c][ln][32] -> dense. Depth-1 prefetch. q3 quantized
// in-register (bit-identical); fc2 butterfly + LDS reduce + per-row log_softmax.
__global__ __launch_bounds__(512) void k_fc12(const ushort_t* q2t, const ushort_t* w3t,
                                              const float* ws, const float* w2,
                                              const float* b2, float* out, int B){
    __shared__ float red[8*16*10];    // [wv][row16][c10]
    int tid = threadIdx.x;
    int lane = tid & 63, wv = tid >> 6;    // wv in [0,8)
    int ln = lane & 15, quad = lane >> 4;
    int gi = blockIdx.x;
    int b0 = gi * 16;

    const ushort_t* asrc = q2t + (size_t)gi*25*512 + ln*32 + quad*8;
    const ushort_t* bsrc = w3t + (size_t)(wv*4)*25*512 + ln*32 + quad*8;

    floatx4 acc[4];
    #pragma unroll
    for (int t = 0; t < 4; ++t) acc[t] = (floatx4){0.f,0.f,0.f,0.f};

    ushort8 aw = *(const ushort8*)(asrc);
    ushort8 bw[4];
    #pragma unroll
    for (int t = 0; t < 4; ++t) bw[t] = *(const ushort8*)(bsrc + t*12800);

    #pragma unroll
    for (int c = 0; c < 25; ++c){
        ushort8 aN; ushort8 bN[4];
        if (c < 24){
            aN = *(const ushort8*)(asrc + (c+1)*512);
            #pragma unroll
            for (int t = 0; t < 4; ++t)
                bN[t] = *(const ushort8*)(bsrc + t*12800 + (c+1)*512);
        }
        #pragma unroll
        for (int t = 0; t < 4; ++t)
            acc[t] = __builtin_amdgcn_mfma_f32_16x16x32_bf16(
                         __builtin_bit_cast(bf16x8, aw), __builtin_bit_cast(bf16x8, bw[t]),
                         acc[t], 0, 0, 0);
        aw = aN;
        #pragma unroll
        for (int t = 0; t < 4; ++t) bw[t] = bN[t];
    }

    // quantize q3 in-register (bit-identical (uint)rintf&255 then S_N3*q)
    float sc3d = ws[1];
    float xf[4][4];
    #pragma unroll
    for (int t = 0; t < 4; ++t){
        int col = wv*64 + t*16 + ln;
        float bias = (col < 500) ? ws[OFF_B3 + col] : 0.0f;
        #pragma unroll
        for (int r = 0; r < 4; ++r){
            float y = fmaxf(fmaf(acc[t][r], sc3d, bias), 0.0f);
            unsigned int q = ((unsigned int)rintf(y)) & 255u;
            xf[r][t] = (col < 500) ? S_N3 * (float)q : 0.0f;
        }
    }

    // fc2: per class c, partial over this lane's 4 cols, butterfly over the 16-lane
    // group (masks 1,2,4,8 stay within quad group), wave-leader writes to LDS.
    #pragma unroll
    for (int c = 0; c < 10; ++c){
        float p[4] = {0.f, 0.f, 0.f, 0.f};
        #pragma unroll
        for (int t = 0; t < 4; ++t){
            int col = wv*64 + t*16 + ln;
            float w = (col < 500) ? w2[c*500 + col] : 0.0f;
            #pragma unroll
            for (int r = 0; r < 4; ++r) p[r] = fmaf(xf[r][t], w, p[r]);
        }
        #pragma unroll
        for (int m = 1; m <= 8; m <<= 1)
            #pragma unroll
            for (int r = 0; r < 4; ++r) p[r] += __shfl_xor(p[r], m);
        if (ln == 0){
            #pragma unroll
            for (int r = 0; r < 4; ++r)
                red[(wv*16 + quad*4 + r)*10 + c] = p[r];
        }
    }
    __syncthreads();

    if (tid < 16){
        int row = tid;
        float lg[10], mx = -INFINITY;
        #pragma unroll
        for (int c = 0; c < 10; ++c){
            float s = b2[c];
            #pragma unroll
            for (int w = 0; w < 8; ++w) s += red[(w*16 + row)*10 + c];
            lg[c] = s; mx = fmaxf(mx, s);
        }
        float sum = 0.0f;
        #pragma unroll
        for (int c = 0; c < 10; ++c) sum += expf(lg[c] - mx);
        float ls = logf(sum);
        #pragma unroll
        for (int c = 0; c < 10; ++c)
            out[(size_t)(b0 + row)*10 + c] = lg[c] - mx - ls;
    }
}

extern "C" void kernel_launch(void* const* d_in, const int* in_sizes, int n_in,
                              void* d_out, int out_size, void* d_ws, size_t ws_size,
                              hipStream_t stream){
    const float* x   = (const float*)d_in[0];
    const float* c1w = (const float*)d_in[1];
    const float* c1b = (const float*)d_in[2];
    const float* c2w = (const float*)d_in[3];
    const float* c2b = (const float*)d_in[4];
    const float* f1w = (const float*)d_in[5];
    const float* f1b = (const float*)d_in[6];
    const float* f2w = (const float*)d_in[7];
    const float* f2b = (const float*)d_in[8];
    int B = in_sizes[0] / 784;

    float* ws = (float*)d_ws;
    float* pmn = ws + OFF_PMN;
    float* pmx = ws + OFF_PMX;
    ushort_t* w1bf = (ushort_t*)((char*)d_ws + W1BF_BYTE);
    ushort_t* w2bf = (ushort_t*)((char*)d_ws + W2BF_BYTE);
    ushort_t* w3bf = (ushort_t*)((char*)d_ws + W3BF_BYTE);
    ushort_t* q2bf = (ushort_t*)((char*)d_ws + Q2_BYTE);
    float* out = (float*)d_out;

    k_minmax<<<72, TPB, 0, stream>>>(c1w, c1b, c2w, c2b, f1w, f1b, pmn, pmx);
    k_make_eff<<<(N_EFF + TPB - 1)/TPB, TPB, 0, stream>>>(c1w, c1b, c2w, c2b, f1w, f1b, pmn, pmx, ws, w1bf, w2bf, w3bf);
    k_conv12<<<B, TPB, 0, stream>>>(x, w1bf, w2bf, ws, q2bf, B);
    k_fc12<<<B/16, 512, 0, stream>>>(q2bf, w3bf, ws, f2w, f2b, out, B);
}